// Round 3
// baseline (522.173 us; speedup 1.0000x reference)
//
#include <hip/hip_runtime.h>
#include <hip/hip_bf16.h>
#include <math.h>

typedef __attribute__((ext_vector_type(8))) short bf16x8;
typedef __attribute__((ext_vector_type(4))) float f32x4;
typedef unsigned short u16;

__device__ __forceinline__ u16 f2b(float f) {
  unsigned u = __float_as_uint(f);
  u = u + 0x7fffu + ((u >> 16) & 1u);   // round-to-nearest-even
  return (u16)(u >> 16);
}
__device__ __forceinline__ float gelu_exact(float x) {
  return 0.5f * x * (1.0f + erff(x * 0.70710678118654752f));
}

// ---------------------------------------------------------------------------
// all three boundary scans in one kernel. grid (B=4, 3), block 1024
__global__ __launch_bounds__(1024) void scan_all_k(
    const int* __restrict__ b0, const int* __restrict__ b1,
    const int* __restrict__ b2, int* __restrict__ starts) {
  __shared__ int sums[1024];
  int lvl = blockIdx.y, row = blockIdx.x;
  const int* bp = (lvl == 0) ? b0 : (lvl == 1) ? b1 : b2;
  int n = (lvl == 0) ? 8192 : (lvl == 1) ? 1024 : 256;
  int nseg = (lvl == 0) ? 1024 : (lvl == 1) ? 256 : 64;
  int* sp = starts + ((lvl == 0) ? 0 : (lvl == 1) ? 4096 : 5120);
  const int* br = bp + (size_t)row * n;
  int chunk = (n + 1023) / 1024;
  int t0 = threadIdx.x * chunk;
  int t1 = t0 + chunk; if (t1 > n) t1 = n;
  if (t0 > n) t0 = n;
  int s = 0;
  for (int t = t0; t < t1; ++t) s += br[t];
  sums[threadIdx.x] = s;
  __syncthreads();
  for (int off = 1; off < 1024; off <<= 1) {
    int v = (threadIdx.x >= off) ? sums[threadIdx.x - off] : 0;
    __syncthreads();
    sums[threadIdx.x] += v;
    __syncthreads();
  }
  int run = sums[threadIdx.x] - s;
  for (int t = t0; t < t1; ++t) {
    if (br[t]) { sp[(size_t)row * nseg + run] = t; ++run; }
  }
}

// ---------------------------------------------------------------------------
// all weight transposes in one kernel: fp32 [K,M] -> bf16 [M,K]
__global__ __launch_bounds__(256) void wtrans_all_k(
    const float* __restrict__ w1, const float* __restrict__ w2,
    const float* __restrict__ ca, u16* __restrict__ w1t,
    u16* __restrict__ w2t, u16* __restrict__ cat) {
  __shared__ float tile[32][33];
  int z = blockIdx.x;
  const float* W; u16* Wt; int K, M, m0, k0;
  if (z < 1536) {
    int mat = z >> 9, tl = z & 511;
    W = w1 + (size_t)mat * 524288; Wt = w1t + (size_t)mat * 524288;
    K = 512; M = 1024; m0 = (tl & 31) * 32; k0 = (tl >> 5) * 32;
  } else if (z < 3072) {
    z -= 1536; int mat = z >> 9, tl = z & 511;
    W = w2 + (size_t)mat * 524288; Wt = w2t + (size_t)mat * 524288;
    K = 1024; M = 512; m0 = (tl & 15) * 32; k0 = (tl >> 4) * 32;
  } else {
    z -= 3072; int mat = z >> 8, tl = z & 255;
    W = ca + (size_t)mat * 262144; Wt = cat + (size_t)mat * 262144;
    K = 512; M = 512; m0 = (tl & 15) * 32; k0 = (tl >> 4) * 32;
  }
  int x = threadIdx.x & 31, y = threadIdx.x >> 5;
  #pragma unroll
  for (int i = 0; i < 32; i += 8)
    tile[y + i][x] = W[(size_t)(k0 + y + i) * M + m0 + x];
  __syncthreads();
  #pragma unroll
  for (int i = 0; i < 32; i += 8)
    Wt[(size_t)(m0 + y + i) * K + k0 + x] = f2b(tile[x][y + i]);
}

// ---------------------------------------------------------------------------
// fused segment-mean-pool + LayerNorm. one wave per segment/token.
// grid (nseg/4, B), block 256. writes fp32 pooled + bf16 LN output.
__global__ __launch_bounds__(256) void pool_ln_k(
    const float* __restrict__ x, const int* __restrict__ starts,
    float* __restrict__ pooled, const float* __restrict__ g,
    const float* __restrict__ bt, u16* __restrict__ lnout,
    int Tin, int nseg) {
  int wv = threadIdx.x >> 6, lane = threadIdx.x & 63;
  int s = blockIdx.x * 4 + wv, b = blockIdx.y;
  int st = starts[(size_t)b * nseg + s];
  int en = (s + 1 < nseg) ? starts[(size_t)b * nseg + s + 1] : Tin;
  const float* xb = x + ((size_t)b * Tin) * 512;
  int d = lane * 8;
  float a[8] = {0.f,0.f,0.f,0.f,0.f,0.f,0.f,0.f};
  for (int t = st; t < en; ++t) {
    const float* row = xb + (size_t)t * 512 + d;
    float4 v0 = *(const float4*)row;
    float4 v1 = *(const float4*)(row + 4);
    a[0]+=v0.x; a[1]+=v0.y; a[2]+=v0.z; a[3]+=v0.w;
    a[4]+=v1.x; a[5]+=v1.y; a[6]+=v1.z; a[7]+=v1.w;
  }
  int cnt = en - st; if (cnt < 1) cnt = 1;
  float ic = 1.0f / (float)cnt;
  #pragma unroll
  for (int i = 0; i < 8; ++i) a[i] *= ic;
  int tok = b * nseg + s;
  float* pr = pooled + (size_t)tok * 512 + d;
  *(float4*)pr = make_float4(a[0], a[1], a[2], a[3]);
  *(float4*)(pr + 4) = make_float4(a[4], a[5], a[6], a[7]);
  // LN
  float sm = a[0]+a[1]+a[2]+a[3]+a[4]+a[5]+a[6]+a[7];
  #pragma unroll
  for (int off = 32; off; off >>= 1) sm += __shfl_xor(sm, off, 64);
  float mean = sm * (1.0f / 512.0f);
  float ss = 0.f;
  #pragma unroll
  for (int i = 0; i < 8; ++i) { a[i] -= mean; ss += a[i]*a[i]; }
  #pragma unroll
  for (int off = 32; off; off >>= 1) ss += __shfl_xor(ss, off, 64);
  float inv = rsqrtf(ss * (1.0f / 512.0f) + 1e-5f);
  float4 g0 = *(const float4*)(g + d), g1 = *(const float4*)(g + d + 4);
  float4 b0 = *(const float4*)(bt + d), b1 = *(const float4*)(bt + d + 4);
  float gg[8] = {g0.x,g0.y,g0.z,g0.w,g1.x,g1.y,g1.z,g1.w};
  float bb[8] = {b0.x,b0.y,b0.z,b0.w,b1.x,b1.y,b1.z,b1.w};
  union { u16 u[8]; uint4 v; } pk;
  #pragma unroll
  for (int i = 0; i < 8; ++i) pk.u[i] = f2b(a[i] * inv * gg[i] + bb[i]);
  *(uint4*)(lnout + (size_t)tok * 512 + d) = pk.v;
}

// ---------------------------------------------------------------------------
// LayerNorm fp32 in -> bf16 out. one wave per token, block=256 (4 tokens)
__global__ __launch_bounds__(256) void ln_kernel(
    const float* __restrict__ x, const float* __restrict__ g,
    const float* __restrict__ bt, u16* __restrict__ y, int ntok) {
  int wave = threadIdx.x >> 6, lane = threadIdx.x & 63;
  int tok = blockIdx.x * 4 + wave;
  if (tok >= ntok) return;
  const float* xr = x + (size_t)tok * 512;
  int d = lane * 8;
  float4 v0 = *(const float4*)(xr + d);
  float4 v1 = *(const float4*)(xr + d + 4);
  float s = v0.x + v0.y + v0.z + v0.w + v1.x + v1.y + v1.z + v1.w;
  #pragma unroll
  for (int off = 32; off; off >>= 1) s += __shfl_xor(s, off, 64);
  float mean = s * (1.0f / 512.0f);
  float a[8] = {v0.x-mean, v0.y-mean, v0.z-mean, v0.w-mean,
                v1.x-mean, v1.y-mean, v1.z-mean, v1.w-mean};
  float ss = 0.f;
  #pragma unroll
  for (int i = 0; i < 8; ++i) ss += a[i]*a[i];
  #pragma unroll
  for (int off = 32; off; off >>= 1) ss += __shfl_xor(ss, off, 64);
  float inv = rsqrtf(ss * (1.0f / 512.0f) + 1e-5f);
  float4 g0 = *(const float4*)(g + d), g1 = *(const float4*)(g + d + 4);
  float4 b0 = *(const float4*)(bt + d), b1 = *(const float4*)(bt + d + 4);
  float gg[8] = {g0.x,g0.y,g0.z,g0.w,g1.x,g1.y,g1.z,g1.w};
  float bb[8] = {b0.x,b0.y,b0.z,b0.w,b1.x,b1.y,b1.z,b1.w};
  union { u16 u[8]; uint4 v; } pk;
  #pragma unroll
  for (int i = 0; i < 8; ++i) pk.u[i] = f2b(a[i] * inv * gg[i] + bb[i]);
  *(uint4*)(y + (size_t)tok * 512 + d) = pk.v;
}

// ---------------------------------------------------------------------------
// V transpose: vsrc bf16 [B*Skv, ld] (V slice) -> vT bf16 [B*H,128,Skv]
__global__ __launch_bounds__(256) void vtrans_kernel(
    const u16* __restrict__ vsrc, int lds_, u16* __restrict__ vT, int Skv) {
  __shared__ u16 tile[32][33];
  int kv0 = blockIdx.x * 32, d0 = blockIdx.y * 32;
  int z = blockIdx.z, b = z >> 2, h = z & 3;
  const u16* src = vsrc + ((size_t)b * Skv) * lds_ + h * 128;
  u16* dst = vT + (size_t)z * 128 * Skv;
  int x = threadIdx.x & 31, y = threadIdx.x >> 5;
  #pragma unroll
  for (int i = 0; i < 32; i += 8)
    tile[y + i][x] = src[(size_t)(kv0 + y + i) * lds_ + d0 + x];
  __syncthreads();
  #pragma unroll
  for (int i = 0; i < 32; i += 8)
    dst[(size_t)(d0 + y + i) * Skv + kv0 + x] = tile[x][y + i];
}

// ---------------------------------------------------------------------------
// MFMA 64x64 tile core with next-tile prefetch. block=256, BK=64, 16x16x32.
__device__ __forceinline__ void mfma_core(
    const u16* __restrict__ A, int lda, const u16* __restrict__ Wt, int ldw,
    int K, u16* AsB, u16* WsB, f32x4 acc[2][2]) {
  int t = threadIdx.x;
  int lane = t & 63, wave = t >> 6;
  int wr = (wave >> 1) * 32, wc = (wave & 1) * 32;
  int lrow = t >> 3;      // 0..31
  int lseg = t & 7;       // 16B segment
  int swz = (lseg * 16) ^ ((lrow & 7) << 4);
  const u16* Ap0 = A + (size_t)lrow * lda + lseg * 8;
  const u16* Ap1 = Ap0 + (size_t)32 * lda;
  const u16* Wp0 = Wt + (size_t)lrow * ldw + lseg * 8;
  const u16* Wp1 = Wp0 + (size_t)32 * ldw;
  uint4 a0 = *(const uint4*)(Ap0);
  uint4 a1 = *(const uint4*)(Ap1);
  uint4 w0 = *(const uint4*)(Wp0);
  uint4 w1 = *(const uint4*)(Wp1);
  for (int k0 = 0; k0 < K; k0 += 64) {
    __syncthreads();
    *(uint4*)((char*)AsB + lrow * 128 + swz) = a0;
    *(uint4*)((char*)AsB + (lrow + 32) * 128 + swz) = a1;
    *(uint4*)((char*)WsB + lrow * 128 + swz) = w0;
    *(uint4*)((char*)WsB + (lrow + 32) * 128 + swz) = w1;
    __syncthreads();
    if (k0 + 64 < K) {
      a0 = *(const uint4*)(Ap0 + k0 + 64);
      a1 = *(const uint4*)(Ap1 + k0 + 64);
      w0 = *(const uint4*)(Wp0 + k0 + 64);
      w1 = *(const uint4*)(Wp1 + k0 + 64);
    }
    #pragma unroll
    for (int ks = 0; ks < 2; ++ks) {
      bf16x8 af[2], bfr[2];
      #pragma unroll
      for (int mi = 0; mi < 2; ++mi) {
        int row = wr + mi * 16 + (lane & 15);
        int cb = (ks * 64 + ((lane >> 4) << 4)) ^ ((row & 7) << 4);
        af[mi] = *(const bf16x8*)((const char*)AsB + row * 128 + cb);
      }
      #pragma unroll
      for (int ni = 0; ni < 2; ++ni) {
        int row = wc + ni * 16 + (lane & 15);
        int cb = (ks * 64 + ((lane >> 4) << 4)) ^ ((row & 7) << 4);
        bfr[ni] = *(const bf16x8*)((const char*)WsB + row * 128 + cb);
      }
      #pragma unroll
      for (int mi = 0; mi < 2; ++mi)
        #pragma unroll
        for (int ni = 0; ni < 2; ++ni)
          acc[mi][ni] = __builtin_amdgcn_mfma_f32_16x16x32_bf16(
              af[mi], bfr[ni], acc[mi][ni], 0, 0, 0);
    }
  }
}

// ---------------------------------------------------------------------------
// generic GEMM: C = act(A @ Wt^T + bias). flags: 1=GELU 2=RES 4=outF 8=outB
__global__ __launch_bounds__(256) void gemm_k(
    const u16* __restrict__ A, int lda, const u16* __restrict__ Wt, int ldw,
    int K, const float* __restrict__ bias, float* __restrict__ Cf,
    u16* __restrict__ Cb, int ldc, int flags) {
  __shared__ u16 As[4096], Ws[4096];
  int n0 = blockIdx.y * 64, m0 = blockIdx.x * 64;
  f32x4 acc[2][2];
  #pragma unroll
  for (int i = 0; i < 2; ++i)
    #pragma unroll
    for (int j = 0; j < 2; ++j) acc[i][j] = (f32x4){0.f, 0.f, 0.f, 0.f};
  mfma_core(A + (size_t)n0 * lda, lda, Wt + (size_t)m0 * ldw, ldw, K, As, Ws, acc);
  int lane = threadIdx.x & 63, wave = threadIdx.x >> 6;
  int wr = (wave >> 1) * 32, wc = (wave & 1) * 32;
  #pragma unroll
  for (int mi = 0; mi < 2; ++mi) {
    #pragma unroll
    for (int ni = 0; ni < 2; ++ni) {
      int col = m0 + wc + ni * 16 + (lane & 15);
      float bv = bias[col];
      #pragma unroll
      for (int j = 0; j < 4; ++j) {
        int row = n0 + wr + mi * 16 + ((lane >> 4) << 2) + j;
        float v = acc[mi][ni][j] + bv;
        if (flags & 1) v = gelu_exact(v);
        size_t idx = (size_t)row * ldc + col;
        if (flags & 2) v += Cf[idx];
        if (flags & 4) Cf[idx] = v;
        if (flags & 8) Cb[idx] = f2b(v);
      }
    }
  }
}

// ---------------------------------------------------------------------------
// fused attention: O = softmax(Q K^T / sqrt(128)) V, no max-subtraction
// (inputs LN'd x 0.02-scale weights => |scores| << 80, exp cannot overflow).
// grid (Sq/64, B*H), block 256 (4 waves; wave w owns q rows [64bx+16w, +16)).
// computes S^T = mfma(K_frag, Q_frag) so P lands in a wave-local LDS slot
// that reads back directly as the PV x32 A-fragment. 16B-slot XOR swizzles
// keep every LDS access <= 2-way (free).
__global__ __launch_bounds__(256) void fattn_k(
    const u16* __restrict__ Q, int ldq, const u16* __restrict__ KV, int ldkv,
    const u16* __restrict__ vT, u16* __restrict__ O, int ldo,
    int Sq, int Skv) {
  __shared__ u16 Ks[64 * 128];     // [kv][128], 256B rows, swizzled 16B slots
  __shared__ u16 Vs[128 * 64];     // [d][64kv], 128B rows, swizzled
  __shared__ u16 Ps[4][16 * 64];   // per-wave P [16 q][64 kv], swizzled
  int z = blockIdx.y, b = z >> 2, h = z & 3;
  int t = threadIdx.x, lane = t & 63, w = t >> 6;
  int g = lane >> 4, ql = lane & 15;
  int q0 = blockIdx.x * 64;
  const float scale = 0.08838834764831845f;
  // Q B-fragments (col=q, k=8g+e+32ks), held in regs for whole kernel
  bf16x8 qf[4];
  {
    const u16* qp = Q + ((size_t)(b * Sq + q0 + 16 * w + ql)) * ldq + h * 128 + g * 8;
    #pragma unroll
    for (int ks = 0; ks < 4; ++ks) qf[ks] = *(const bf16x8*)(qp + 32 * ks);
  }
  f32x4 o[8];
  #pragma unroll
  for (int i = 0; i < 8; ++i) o[i] = (f32x4){0.f, 0.f, 0.f, 0.f};
  float lsum = 0.f;
  for (int kv0 = 0; kv0 < Skv; kv0 += 64) {
    // stage K tile (64x256B) and V^T tile (128x128B), reg-staged
    uint4 kreg[4], vreg[4];
    const u16* kbase = KV + ((size_t)(b * Skv + kv0)) * ldkv + h * 128;
    const u16* vbase = vT + (size_t)z * 128 * Skv + kv0;
    #pragma unroll
    for (int i = 0; i < 4; ++i) {
      int idx = t + i * 256;
      kreg[i] = *(const uint4*)(kbase + (size_t)(idx >> 4) * ldkv + (idx & 15) * 8);
      vreg[i] = *(const uint4*)(vbase + (size_t)(idx >> 3) * Skv + (idx & 7) * 8);
    }
    __syncthreads();
    #pragma unroll
    for (int i = 0; i < 4; ++i) {
      int idx = t + i * 256;
      int kr = idx >> 4, kss = idx & 15;
      *(uint4*)((char*)Ks + kr * 256 + (((kss ^ (kr & 7))) << 4)) = kreg[i];
      int vd = idx >> 3, vs = idx & 7;
      *(uint4*)((char*)Vs + vd * 128 + (((vs ^ (vd & 7))) << 4)) = vreg[i];
    }
    __syncthreads();
    // S^T tiles: C[kv=16kvt+4g+r][q=ql]
    float rs = 0.f;
    #pragma unroll
    for (int kvt = 0; kvt < 4; ++kvt) {
      f32x4 acc = (f32x4){0.f, 0.f, 0.f, 0.f};
      int row = kvt * 16 + ql;
      #pragma unroll
      for (int ks = 0; ks < 4; ++ks) {
        int seg = (4 * ks + g) ^ (row & 7);
        bf16x8 kf = *(const bf16x8*)((const char*)Ks + row * 256 + seg * 16);
        acc = __builtin_amdgcn_mfma_f32_16x16x32_bf16(kf, qf[ks], acc, 0, 0, 0);
      }
      // P = exp(S*scale), pack 4 bf16 -> 8B wave-local LDS store
      float e0 = __expf(acc[0] * scale), e1 = __expf(acc[1] * scale);
      float e2 = __expf(acc[2] * scale), e3 = __expf(acc[3] * scale);
      rs += e0 + e1 + e2 + e3;
      unsigned lo = (unsigned)f2b(e0) | ((unsigned)f2b(e1) << 16);
      unsigned hi = (unsigned)f2b(e2) | ((unsigned)f2b(e3) << 16);
      int slot = (2 * kvt + (g >> 1)) ^ (ql & 7);
      *(uint2*)((char*)Ps[w] + ql * 128 + slot * 16 + 8 * (g & 1)) =
          make_uint2(lo, hi);
    }
    // row sums (per q=ql; groups g hold disjoint kv -> xor-reduce 16,32)
    rs += __shfl_xor(rs, 16, 64);
    rs += __shfl_xor(rs, 32, 64);
    lsum += rs;
    // PV: o[dt] += P(16q x 64kv) @ V^T, x32 MFMA
    #pragma unroll
    for (int kh = 0; kh < 2; ++kh) {
      int slot = (4 * kh + g) ^ (ql & 7);
      bf16x8 pa = *(const bf16x8*)((const char*)Ps[w] + ql * 128 + slot * 16);
      #pragma unroll
      for (int dt = 0; dt < 8; ++dt) {
        int dr = dt * 16 + ql;
        bf16x8 vf = *(const bf16x8*)((const char*)Vs + dr * 128 +
                                     (((4 * kh + g) ^ (dr & 7)) << 4));
        o[dt] = __builtin_amdgcn_mfma_f32_16x16x32_bf16(pa, vf, o[dt], 0, 0, 0);
      }
    }
  }
  // normalize rows (o row index = 4g+r, lsum lives at lane ql==4g+r) + store
  float linv[4];
  #pragma unroll
  for (int r = 0; r < 4; ++r) linv[r] = 1.0f / __shfl(lsum, 4 * g + r, 64);
  u16* ob = O + ((size_t)(b * Sq + q0 + 16 * w)) * ldo + h * 128;
  #pragma unroll
  for (int dt = 0; dt < 8; ++dt)
    #pragma unroll
    for (int r = 0; r < 4; ++r)
      ob[(size_t)(4 * g + r) * ldo + dt * 16 + ql] = f2b(o[dt][r] * linv[r]);
}

// ---------------------------------------------------------------------------
extern "C" void kernel_launch(void* const* d_in, const int* in_sizes, int n_in,
                              void* d_out, int out_size, void* d_ws, size_t ws_size,
                              hipStream_t stream) {
  (void)in_sizes; (void)n_in; (void)out_size; (void)ws_size;
  const float* h_bytes  = (const float*)d_in[0];
  const int*   b0       = (const int*)d_in[1];
  const int*   b1       = (const int*)d_in[2];
  const int*   b2       = (const int*)d_in[3];
  const float* mlp_ln_g = (const float*)d_in[4];
  const float* mlp_ln_b = (const float*)d_in[5];
  const float* mlp_w1   = (const float*)d_in[6];
  const float* mlp_b1   = (const float*)d_in[7];
  const float* mlp_w2   = (const float*)d_in[8];
  const float* mlp_b2   = (const float*)d_in[9];
  const float* ca_w     = (const float*)d_in[10];
  const float* ca_b     = (const float*)d_in[11];
  const float* ca_ln_g  = (const float*)d_in[12];
  const float* ca_ln_b  = (const float*)d_in[13];

  float* out0 = (float*)d_out;
  float* out1 = out0 + 4 * 1024 * 512;
  float* out2 = out1 + 4 * 256 * 512;

  char* wsb = (char*)d_ws;
  const size_t MB = 1048576;
  u16* w1t   = (u16*)(wsb + 0 * MB);    // 3 MB  [3][1024][512]
  u16* w2t   = (u16*)(wsb + 3 * MB);    // 3 MB  [3][512][1024]
  u16* cat   = (u16*)(wsb + 6 * MB);    // 8 MB  [16][512][512]
  u16* m0b   = (u16*)(wsb + 14 * MB);   // 4 MB  bf16 mirror of out0
  u16* m1b   = (u16*)(wsb + 18 * MB);   // 1 MB  mirror of out1
  u16* m2b   = (u16*)(wsb + 19 * MB);   // 0.25 MB mirror of out2
  u16* lnbuf = (u16*)(wsb + 20 * MB);   // 4 MB
  u16* hbuf  = (u16*)(wsb + 24 * MB);   // 8 MB
  u16* qb    = (u16*)(wsb + 32 * MB);   // 4 MB
  u16* kvbuf = (u16*)(wsb + 36 * MB);   // 8 MB  [N][1024] k|v
  u16* vT    = (u16*)(wsb + 44 * MB);   // 4 MB  [16][128][Skv]
  u16* abuf  = (u16*)(wsb + 48 * MB);   // 4 MB
  int* starts  = (int*)(wsb + 52 * MB); // s0 @0, s1 @4096, s2 @5120
  int* starts0 = starts;
  int* starts1 = starts + 4096;
  int* starts2 = starts + 5120;

  wtrans_all_k<<<7168, 256, 0, stream>>>(mlp_w1, mlp_w2, ca_w, w1t, w2t, cat);
  scan_all_k<<<dim3(4, 3), 1024, 0, stream>>>(b0, b1, b2, starts);

  // ---- levels: fused pool+LN, then MLP (mirror written by gemm2)
  auto mlp = [&](float* X, u16* mir, int Ntok, int lvl) {
    gemm_k<<<dim3(16, Ntok / 64), 256, 0, stream>>>(
        lnbuf, 512, w1t + (size_t)lvl * 524288, 512, 512,
        mlp_b1 + lvl * 1024, nullptr, hbuf, 1024, 1 | 8);
    gemm_k<<<dim3(8, Ntok / 64), 256, 0, stream>>>(
        hbuf, 1024, w2t + (size_t)lvl * 524288, 1024, 1024,
        mlp_b2 + lvl * 512, X, mir, 512, 2 | 4 | 8);
  };
  pool_ln_k<<<dim3(256, 4), 256, 0, stream>>>(h_bytes, starts0, out0,
      mlp_ln_g, mlp_ln_b, lnbuf, 8192, 1024);
  mlp(out0, m0b, 4096, 0);
  pool_ln_k<<<dim3(64, 4), 256, 0, stream>>>(out0, starts1, out1,
      mlp_ln_g + 512, mlp_ln_b + 512, lnbuf, 1024, 256);
  mlp(out1, m1b, 1024, 1);
  pool_ln_k<<<dim3(16, 4), 256, 0, stream>>>(out1, starts2, out2,
      mlp_ln_g + 1024, mlp_ln_b + 1024, lnbuf, 256, 64);
  mlp(out2, m2b, 256, 2);

  // ---- cross-level refinement
  // F fp32/mirror mf, Cc fp32/mirror mc, nf/nc segments per batch
  auto cross = [&](int i, float* F, u16* mf, float* Cc, u16* mc, int nf, int nc) {
    u16* cw = cat + (size_t)i * 8 * 262144;
    const float* bb = ca_b + (size_t)i * 8 * 512;
    const float* lg = ca_ln_g + (size_t)i * 2 * 512;
    const float* lb = ca_ln_b + (size_t)i * 2 * 512;
    int Nf = 4 * nf, Nc = 4 * nc;
    // bottom-up: q = ln(F), kv from coarse mirror
    ln_kernel<<<Nf / 4, 256, 0, stream>>>(F, lg, lb, lnbuf, Nf);
    gemm_k<<<dim3(8, Nf / 64), 256, 0, stream>>>(lnbuf, 512, cw, 512, 512,
        bb, nullptr, qb, 512, 8);
    gemm_k<<<dim3(16, Nc / 64), 256, 0, stream>>>(mc, 512, cw + 262144, 512, 512,
        bb + 512, nullptr, kvbuf, 1024, 8);
    vtrans_kernel<<<dim3(nc / 32, 4, 16), 256, 0, stream>>>(kvbuf + 512, 1024, vT, nc);
    fattn_k<<<dim3(nf / 64, 16), 256, 0, stream>>>(qb, 512, kvbuf, 1024, vT,
        abuf, 512, nf, nc);
    gemm_k<<<dim3(8, Nf / 64), 256, 0, stream>>>(abuf, 512, cw + 3 * 262144, 512, 512,
        bb + 3 * 512, F, mf, 512, 2 | 4 | 8);
    // top-down: q = ln(Cc), kv from updated fine mirror
    ln_kernel<<<Nc / 4, 256, 0, stream>>>(Cc, lg + 512, lb + 512, lnbuf, Nc);
    gemm_k<<<dim3(8, Nc / 64), 256, 0, stream>>>(lnbuf, 512, cw + 4 * 262144, 512, 512,
        bb + 4 * 512, nullptr, qb, 512, 8);
    gemm_k<<<dim3(16, Nf / 64), 256, 0, stream>>>(mf, 512, cw + 5 * 262144, 512, 512,
        bb + 5 * 512, nullptr, kvbuf, 1024, 8);
    vtrans_kernel<<<dim3(nf / 32, 4, 16), 256, 0, stream>>>(kvbuf + 512, 1024, vT, nf);
    fattn_k<<<dim3(nc / 64, 16), 256, 0, stream>>>(qb, 512, kvbuf, 1024, vT,
        abuf, 512, nc, nf);
    gemm_k<<<dim3(8, Nc / 64), 256, 0, stream>>>(abuf, 512, cw + 7 * 262144, 512, 512,
        bb + 7 * 512, Cc, mc, 512, 2 | 4 | 8);
  };
  cross(1, out1, m1b, out2, m2b, 256, 64);
  cross(0, out0, m0b, out1, m1b, 1024, 256);
}

// Round 5
// 442.991 us; speedup vs baseline: 1.1787x; 1.1787x over previous
//
#include <hip/hip_runtime.h>
#include <hip/hip_bf16.h>
#include <math.h>

typedef __attribute__((ext_vector_type(8))) short bf16x8;
typedef __attribute__((ext_vector_type(4))) float f32x4;
typedef unsigned short u16;

__device__ __forceinline__ u16 f2b(float f) {
  unsigned u = __float_as_uint(f);
  u = u + 0x7fffu + ((u >> 16) & 1u);   // round-to-nearest-even
  return (u16)(u >> 16);
}
__device__ __forceinline__ float gelu_exact(float x) {
  return 0.5f * x * (1.0f + erff(x * 0.70710678118654752f));
}

// ---------------------------------------------------------------------------
// all three boundary scans in one kernel. grid (B=4, 3), block 1024
__global__ __launch_bounds__(1024) void scan_all_k(
    const int* __restrict__ b0, const int* __restrict__ b1,
    const int* __restrict__ b2, int* __restrict__ starts) {
  __shared__ int sums[1024];
  int lvl = blockIdx.y, row = blockIdx.x;
  const int* bp = (lvl == 0) ? b0 : (lvl == 1) ? b1 : b2;
  int n = (lvl == 0) ? 8192 : (lvl == 1) ? 1024 : 256;
  int nseg = (lvl == 0) ? 1024 : (lvl == 1) ? 256 : 64;
  int* sp = starts + ((lvl == 0) ? 0 : (lvl == 1) ? 4096 : 5120);
  const int* br = bp + (size_t)row * n;
  int chunk = (n + 1023) / 1024;
  int t0 = threadIdx.x * chunk;
  int t1 = t0 + chunk; if (t1 > n) t1 = n;
  if (t0 > n) t0 = n;
  int s = 0;
  for (int t = t0; t < t1; ++t) s += br[t];
  sums[threadIdx.x] = s;
  __syncthreads();
  for (int off = 1; off < 1024; off <<= 1) {
    int v = (threadIdx.x >= off) ? sums[threadIdx.x - off] : 0;
    __syncthreads();
    sums[threadIdx.x] += v;
    __syncthreads();
  }
  int run = sums[threadIdx.x] - s;
  for (int t = t0; t < t1; ++t) {
    if (br[t]) { sp[(size_t)row * nseg + run] = t; ++run; }
  }
}

// ---------------------------------------------------------------------------
// all weight transposes in one kernel: fp32 [K,M] -> bf16 [M,K]
__global__ __launch_bounds__(256) void wtrans_all_k(
    const float* __restrict__ w1, const float* __restrict__ w2,
    const float* __restrict__ ca, u16* __restrict__ w1t,
    u16* __restrict__ w2t, u16* __restrict__ cat) {
  __shared__ float tile[32][33];
  int z = blockIdx.x;
  const float* W; u16* Wt; int K, M, m0, k0;
  if (z < 1536) {
    int mat = z >> 9, tl = z & 511;
    W = w1 + (size_t)mat * 524288; Wt = w1t + (size_t)mat * 524288;
    K = 512; M = 1024; m0 = (tl & 31) * 32; k0 = (tl >> 5) * 32;
  } else if (z < 3072) {
    z -= 1536; int mat = z >> 9, tl = z & 511;
    W = w2 + (size_t)mat * 524288; Wt = w2t + (size_t)mat * 524288;
    K = 1024; M = 512; m0 = (tl & 15) * 32; k0 = (tl >> 4) * 32;
  } else {
    z -= 3072; int mat = z >> 8, tl = z & 255;
    W = ca + (size_t)mat * 262144; Wt = cat + (size_t)mat * 262144;
    K = 512; M = 512; m0 = (tl & 15) * 32; k0 = (tl >> 4) * 32;
  }
  int x = threadIdx.x & 31, y = threadIdx.x >> 5;
  #pragma unroll
  for (int i = 0; i < 32; i += 8)
    tile[y + i][x] = W[(size_t)(k0 + y + i) * M + m0 + x];
  __syncthreads();
  #pragma unroll
  for (int i = 0; i < 32; i += 8)
    Wt[(size_t)(m0 + y + i) * K + k0 + x] = f2b(tile[x][y + i]);
}

// ---------------------------------------------------------------------------
// fused segment-mean-pool + LayerNorm. one wave per segment/token.
// grid (nseg/4, B), block 256. writes fp32 pooled + bf16 LN output.
__global__ __launch_bounds__(256) void pool_ln_k(
    const float* __restrict__ x, const int* __restrict__ starts,
    float* __restrict__ pooled, const float* __restrict__ g,
    const float* __restrict__ bt, u16* __restrict__ lnout,
    int Tin, int nseg) {
  int wv = threadIdx.x >> 6, lane = threadIdx.x & 63;
  int s = blockIdx.x * 4 + wv, b = blockIdx.y;
  int st = starts[(size_t)b * nseg + s];
  int en = (s + 1 < nseg) ? starts[(size_t)b * nseg + s + 1] : Tin;
  const float* xb = x + ((size_t)b * Tin) * 512;
  int d = lane * 8;
  float a[8] = {0.f,0.f,0.f,0.f,0.f,0.f,0.f,0.f};
  for (int t = st; t < en; ++t) {
    const float* row = xb + (size_t)t * 512 + d;
    float4 v0 = *(const float4*)row;
    float4 v1 = *(const float4*)(row + 4);
    a[0]+=v0.x; a[1]+=v0.y; a[2]+=v0.z; a[3]+=v0.w;
    a[4]+=v1.x; a[5]+=v1.y; a[6]+=v1.z; a[7]+=v1.w;
  }
  int cnt = en - st; if (cnt < 1) cnt = 1;
  float ic = 1.0f / (float)cnt;
  #pragma unroll
  for (int i = 0; i < 8; ++i) a[i] *= ic;
  int tok = b * nseg + s;
  float* pr = pooled + (size_t)tok * 512 + d;
  *(float4*)pr = make_float4(a[0], a[1], a[2], a[3]);
  *(float4*)(pr + 4) = make_float4(a[4], a[5], a[6], a[7]);
  // LN
  float sm = a[0]+a[1]+a[2]+a[3]+a[4]+a[5]+a[6]+a[7];
  #pragma unroll
  for (int off = 32; off; off >>= 1) sm += __shfl_xor(sm, off, 64);
  float mean = sm * (1.0f / 512.0f);
  float ss = 0.f;
  #pragma unroll
  for (int i = 0; i < 8; ++i) { a[i] -= mean; ss += a[i]*a[i]; }
  #pragma unroll
  for (int off = 32; off; off >>= 1) ss += __shfl_xor(ss, off, 64);
  float inv = rsqrtf(ss * (1.0f / 512.0f) + 1e-5f);
  float4 g0 = *(const float4*)(g + d), g1 = *(const float4*)(g + d + 4);
  float4 b0 = *(const float4*)(bt + d), b1 = *(const float4*)(bt + d + 4);
  float gg[8] = {g0.x,g0.y,g0.z,g0.w,g1.x,g1.y,g1.z,g1.w};
  float bb[8] = {b0.x,b0.y,b0.z,b0.w,b1.x,b1.y,b1.z,b1.w};
  union { u16 u[8]; uint4 v; } pk;
  #pragma unroll
  for (int i = 0; i < 8; ++i) pk.u[i] = f2b(a[i] * inv * gg[i] + bb[i]);
  *(uint4*)(lnout + (size_t)tok * 512 + d) = pk.v;
}

// ---------------------------------------------------------------------------
// LayerNorm fp32 in -> bf16 out. one wave per token, block=256 (4 tokens)
__global__ __launch_bounds__(256) void ln_kernel(
    const float* __restrict__ x, const float* __restrict__ g,
    const float* __restrict__ bt, u16* __restrict__ y, int ntok) {
  int wave = threadIdx.x >> 6, lane = threadIdx.x & 63;
  int tok = blockIdx.x * 4 + wave;
  if (tok >= ntok) return;
  const float* xr = x + (size_t)tok * 512;
  int d = lane * 8;
  float4 v0 = *(const float4*)(xr + d);
  float4 v1 = *(const float4*)(xr + d + 4);
  float s = v0.x + v0.y + v0.z + v0.w + v1.x + v1.y + v1.z + v1.w;
  #pragma unroll
  for (int off = 32; off; off >>= 1) s += __shfl_xor(s, off, 64);
  float mean = s * (1.0f / 512.0f);
  float a[8] = {v0.x-mean, v0.y-mean, v0.z-mean, v0.w-mean,
                v1.x-mean, v1.y-mean, v1.z-mean, v1.w-mean};
  float ss = 0.f;
  #pragma unroll
  for (int i = 0; i < 8; ++i) ss += a[i]*a[i];
  #pragma unroll
  for (int off = 32; off; off >>= 1) ss += __shfl_xor(ss, off, 64);
  float inv = rsqrtf(ss * (1.0f / 512.0f) + 1e-5f);
  float4 g0 = *(const float4*)(g + d), g1 = *(const float4*)(g + d + 4);
  float4 b0 = *(const float4*)(bt + d), b1 = *(const float4*)(bt + d + 4);
  float gg[8] = {g0.x,g0.y,g0.z,g0.w,g1.x,g1.y,g1.z,g1.w};
  float bb[8] = {b0.x,b0.y,b0.z,b0.w,b1.x,b1.y,b1.z,b1.w};
  union { u16 u[8]; uint4 v; } pk;
  #pragma unroll
  for (int i = 0; i < 8; ++i) pk.u[i] = f2b(a[i] * inv * gg[i] + bb[i]);
  *(uint4*)(y + (size_t)tok * 512 + d) = pk.v;
}

// ---------------------------------------------------------------------------
// V transpose: vsrc bf16 [B*Skv, ld] (V slice) -> vT bf16 [B*H,128,Skv]
__global__ __launch_bounds__(256) void vtrans_kernel(
    const u16* __restrict__ vsrc, int lds_, u16* __restrict__ vT, int Skv) {
  __shared__ u16 tile[32][33];
  int kv0 = blockIdx.x * 32, d0 = blockIdx.y * 32;
  int z = blockIdx.z, b = z >> 2, h = z & 3;
  const u16* src = vsrc + ((size_t)b * Skv) * lds_ + h * 128;
  u16* dst = vT + (size_t)z * 128 * Skv;
  int x = threadIdx.x & 31, y = threadIdx.x >> 5;
  #pragma unroll
  for (int i = 0; i < 32; i += 8)
    tile[y + i][x] = src[(size_t)(kv0 + y + i) * lds_ + d0 + x];
  __syncthreads();
  #pragma unroll
  for (int i = 0; i < 32; i += 8)
    dst[(size_t)(d0 + y + i) * Skv + kv0 + x] = tile[x][y + i];
}

// ---------------------------------------------------------------------------
// MFMA 64x64 tile core with next-tile prefetch. block=256, BK=64, 16x16x32.
__device__ __forceinline__ void mfma_core(
    const u16* __restrict__ A, int lda, const u16* __restrict__ Wt, int ldw,
    int K, u16* AsB, u16* WsB, f32x4 acc[2][2]) {
  int t = threadIdx.x;
  int lane = t & 63, wave = t >> 6;
  int wr = (wave >> 1) * 32, wc = (wave & 1) * 32;
  int lrow = t >> 3;      // 0..31
  int lseg = t & 7;       // 16B segment
  int swz = (lseg * 16) ^ ((lrow & 7) << 4);
  const u16* Ap0 = A + (size_t)lrow * lda + lseg * 8;
  const u16* Ap1 = Ap0 + (size_t)32 * lda;
  const u16* Wp0 = Wt + (size_t)lrow * ldw + lseg * 8;
  const u16* Wp1 = Wp0 + (size_t)32 * ldw;
  uint4 a0 = *(const uint4*)(Ap0);
  uint4 a1 = *(const uint4*)(Ap1);
  uint4 w0 = *(const uint4*)(Wp0);
  uint4 w1 = *(const uint4*)(Wp1);
  for (int k0 = 0; k0 < K; k0 += 64) {
    __syncthreads();
    *(uint4*)((char*)AsB + lrow * 128 + swz) = a0;
    *(uint4*)((char*)AsB + (lrow + 32) * 128 + swz) = a1;
    *(uint4*)((char*)WsB + lrow * 128 + swz) = w0;
    *(uint4*)((char*)WsB + (lrow + 32) * 128 + swz) = w1;
    __syncthreads();
    if (k0 + 64 < K) {
      a0 = *(const uint4*)(Ap0 + k0 + 64);
      a1 = *(const uint4*)(Ap1 + k0 + 64);
      w0 = *(const uint4*)(Wp0 + k0 + 64);
      w1 = *(const uint4*)(Wp1 + k0 + 64);
    }
    #pragma unroll
    for (int ks = 0; ks < 2; ++ks) {
      bf16x8 af[2], bfr[2];
      #pragma unroll
      for (int mi = 0; mi < 2; ++mi) {
        int row = wr + mi * 16 + (lane & 15);
        int cb = (ks * 64 + ((lane >> 4) << 4)) ^ ((row & 7) << 4);
        af[mi] = *(const bf16x8*)((const char*)AsB + row * 128 + cb);
      }
      #pragma unroll
      for (int ni = 0; ni < 2; ++ni) {
        int row = wc + ni * 16 + (lane & 15);
        int cb = (ks * 64 + ((lane >> 4) << 4)) ^ ((row & 7) << 4);
        bfr[ni] = *(const bf16x8*)((const char*)WsB + row * 128 + cb);
      }
      #pragma unroll
      for (int mi = 0; mi < 2; ++mi)
        #pragma unroll
        for (int ni = 0; ni < 2; ++ni)
          acc[mi][ni] = __builtin_amdgcn_mfma_f32_16x16x32_bf16(
              af[mi], bfr[ni], acc[mi][ni], 0, 0, 0);
    }
  }
}

// ---------------------------------------------------------------------------
// generic GEMM: C = act(A @ Wt^T + bias). flags: 1=GELU 2=RES 4=outF 8=outB
__global__ __launch_bounds__(256) void gemm_k(
    const u16* __restrict__ A, int lda, const u16* __restrict__ Wt, int ldw,
    int K, const float* __restrict__ bias, float* __restrict__ Cf,
    u16* __restrict__ Cb, int ldc, int flags) {
  __shared__ u16 As[4096], Ws[4096];
  int n0 = blockIdx.y * 64, m0 = blockIdx.x * 64;
  f32x4 acc[2][2];
  #pragma unroll
  for (int i = 0; i < 2; ++i)
    #pragma unroll
    for (int j = 0; j < 2; ++j) acc[i][j] = (f32x4){0.f, 0.f, 0.f, 0.f};
  mfma_core(A + (size_t)n0 * lda, lda, Wt + (size_t)m0 * ldw, ldw, K, As, Ws, acc);
  int lane = threadIdx.x & 63, wave = threadIdx.x >> 6;
  int wr = (wave >> 1) * 32, wc = (wave & 1) * 32;
  #pragma unroll
  for (int mi = 0; mi < 2; ++mi) {
    #pragma unroll
    for (int ni = 0; ni < 2; ++ni) {
      int col = m0 + wc + ni * 16 + (lane & 15);
      float bv = bias[col];
      #pragma unroll
      for (int j = 0; j < 4; ++j) {
        int row = n0 + wr + mi * 16 + ((lane >> 4) << 2) + j;
        float v = acc[mi][ni][j] + bv;
        if (flags & 1) v = gelu_exact(v);
        size_t idx = (size_t)row * ldc + col;
        if (flags & 2) v += Cf[idx];
        if (flags & 4) Cf[idx] = v;
        if (flags & 8) Cb[idx] = f2b(v);
      }
    }
  }
}

// ---------------------------------------------------------------------------
// fused attention, split-KV, barrier-free main loop.
// O = softmax(Q K^T / sqrt(128)) V with no max-subtraction (LN'd inputs x
// 0.02-scale weights => |scores| << 80): partial (o, lsum) over kv chunks
// combine by pure addition.
// grid (Sq/16, B*H), block 256 = 4 waves. Block owns 16 q rows; wave w owns
// kv tiles t = w, w+4, ... (64 kv each). K and V^T fragments load DIRECTLY
// from global (L2-resident); P transposes through wave-private LDS (in-order
// DS pipe, no barrier). One __syncthreads total, for the 4-wave combine.
__global__ __launch_bounds__(256) void fattn_k(
    const u16* __restrict__ Q, int ldq, const u16* __restrict__ KV, int ldkv,
    const u16* __restrict__ vT, u16* __restrict__ O, int ldo,
    int Sq, int Skv) {
  __shared__ u16 Ps[4][16 * 64];       // per-wave P [16 q][64 kv], swizzled
  __shared__ float Ob[3][8][16][16];   // waves 1..3 partial O [dt][q][d]
  __shared__ float Ls[3][16];          // waves 1..3 partial row sums
  int z = blockIdx.y, b = z >> 2, h = z & 3;
  int t = threadIdx.x, lane = t & 63, w = t >> 6;
  int g = lane >> 4, ql = lane & 15;
  int q0 = blockIdx.x * 16;
  const float scale = 0.08838834764831845f;
  // Q B-fragments (col=q=ql, k=8g+e+32ks), in regs for whole kernel
  bf16x8 qf[4];
  {
    const u16* qp = Q + ((size_t)(b * Sq + q0 + ql)) * ldq + h * 128 + g * 8;
    #pragma unroll
    for (int ks = 0; ks < 4; ++ks) qf[ks] = *(const bf16x8*)(qp + 32 * ks);
  }
  f32x4 o[8];
  #pragma unroll
  for (int i = 0; i < 8; ++i) o[i] = (f32x4){0.f, 0.f, 0.f, 0.f};
  float lsum = 0.f;
  int ntiles = Skv >> 6;
  const u16* kbaseA = KV + ((size_t)b * Skv + ql) * ldkv + h * 128 + g * 8;
  const u16* vbase = vT + (size_t)z * 128 * Skv;
  for (int tt = w; tt < ntiles; tt += 4) {
    int kv0 = tt * 64;
    // S^T tiles: C[kv=16kvt+4g+r][q=ql], K A-frags direct from global
    float rs = 0.f;
    #pragma unroll
    for (int kvt = 0; kvt < 4; ++kvt) {
      const u16* kp = kbaseA + (size_t)(kv0 + kvt * 16) * ldkv;
      f32x4 acc = (f32x4){0.f, 0.f, 0.f, 0.f};
      #pragma unroll
      for (int ks = 0; ks < 4; ++ks) {
        bf16x8 kf = *(const bf16x8*)(kp + 32 * ks);
        acc = __builtin_amdgcn_mfma_f32_16x16x32_bf16(kf, qf[ks], acc, 0, 0, 0);
      }
      float e0 = __expf(acc[0] * scale), e1 = __expf(acc[1] * scale);
      float e2 = __expf(acc[2] * scale), e3 = __expf(acc[3] * scale);
      rs += e0 + e1 + e2 + e3;
      unsigned lo = (unsigned)f2b(e0) | ((unsigned)f2b(e1) << 16);
      unsigned hi = (unsigned)f2b(e2) | ((unsigned)f2b(e3) << 16);
      int slot = (2 * kvt + (g >> 1)) ^ (ql & 7);
      *(uint2*)((char*)Ps[w] + ql * 128 + slot * 16 + 8 * (g & 1)) =
          make_uint2(lo, hi);
    }
    // row sums (per q=ql; groups g hold disjoint kv)
    rs += __shfl_xor(rs, 16, 64);
    rs += __shfl_xor(rs, 32, 64);
    lsum += rs;
    // PV: o[dt] += P(16q x 64kv) @ V^T, V^T B-frags direct from global
    #pragma unroll
    for (int kh = 0; kh < 2; ++kh) {
      int slot = (4 * kh + g) ^ (ql & 7);
      bf16x8 pa = *(const bf16x8*)((const char*)Ps[w] + ql * 128 + slot * 16);
      #pragma unroll
      for (int dt = 0; dt < 8; ++dt) {
        bf16x8 vf = *(const bf16x8*)(vbase + (size_t)(dt * 16 + ql) * Skv +
                                     kv0 + kh * 32 + g * 8);
        o[dt] = __builtin_amdgcn_mfma_f32_16x16x32_bf16(pa, vf, o[dt], 0, 0, 0);
      }
    }
  }
  // combine 4 waves' partials (pure addition: no softmax rescaling needed)
  if (w) {
    #pragma unroll
    for (int dt = 0; dt < 8; ++dt)
      #pragma unroll
      for (int j = 0; j < 4; ++j)
        Ob[w - 1][dt][4 * g + j][ql] = o[dt][j];
    if (g == 0) Ls[w - 1][ql] = lsum;
  }
  __syncthreads();
  if (w == 0) {
    float lt = lsum + Ls[0][ql] + Ls[1][ql] + Ls[2][ql];
    float linv[4];
    #pragma unroll
    for (int r = 0; r < 4; ++r) linv[r] = 1.0f / __shfl(lt, 4 * g + r, 64);
    u16* ob = O + ((size_t)(b * Sq + q0)) * ldo + h * 128;
    #pragma unroll
    for (int dt = 0; dt < 8; ++dt)
      #pragma unroll
      for (int r = 0; r < 4; ++r) {
        float v = o[dt][r] + Ob[0][dt][4 * g + r][ql] +
                  Ob[1][dt][4 * g + r][ql] + Ob[2][dt][4 * g + r][ql];
        ob[(size_t)(4 * g + r) * ldo + dt * 16 + ql] = f2b(v * linv[r]);
      }
  }
}

// ---------------------------------------------------------------------------
extern "C" void kernel_launch(void* const* d_in, const int* in_sizes, int n_in,
                              void* d_out, int out_size, void* d_ws, size_t ws_size,
                              hipStream_t stream) {
  (void)in_sizes; (void)n_in; (void)out_size; (void)ws_size;
  const float* h_bytes  = (const float*)d_in[0];
  const int*   b0       = (const int*)d_in[1];
  const int*   b1       = (const int*)d_in[2];
  const int*   b2       = (const int*)d_in[3];
  const float* mlp_ln_g = (const float*)d_in[4];
  const float* mlp_ln_b = (const float*)d_in[5];
  const float* mlp_w1   = (const float*)d_in[6];
  const float* mlp_b1   = (const float*)d_in[7];
  const float* mlp_w2   = (const float*)d_in[8];
  const float* mlp_b2   = (const float*)d_in[9];
  const float* ca_w     = (const float*)d_in[10];
  const float* ca_b     = (const float*)d_in[11];
  const float* ca_ln_g  = (const float*)d_in[12];
  const float* ca_ln_b  = (const float*)d_in[13];

  float* out0 = (float*)d_out;
  float* out1 = out0 + 4 * 1024 * 512;
  float* out2 = out1 + 4 * 256 * 512;

  char* wsb = (char*)d_ws;
  const size_t MB = 1048576;
  u16* w1t   = (u16*)(wsb + 0 * MB);    // 3 MB  [3][1024][512]
  u16* w2t   = (u16*)(wsb + 3 * MB);    // 3 MB  [3][512][1024]
  u16* cat   = (u16*)(wsb + 6 * MB);    // 8 MB  [16][512][512]
  u16* m0b   = (u16*)(wsb + 14 * MB);   // 4 MB  bf16 mirror of out0
  u16* m1b   = (u16*)(wsb + 18 * MB);   // 1 MB  mirror of out1
  u16* m2b   = (u16*)(wsb + 19 * MB);   // 0.25 MB mirror of out2
  u16* lnbuf = (u16*)(wsb + 20 * MB);   // 4 MB
  u16* hbuf  = (u16*)(wsb + 24 * MB);   // 8 MB
  u16* qb    = (u16*)(wsb + 32 * MB);   // 4 MB
  u16* kvbuf = (u16*)(wsb + 36 * MB);   // 8 MB  [N][1024] k|v
  u16* vT    = (u16*)(wsb + 44 * MB);   // 4 MB  [16][128][Skv]
  u16* abuf  = (u16*)(wsb + 48 * MB);   // 4 MB
  int* starts  = (int*)(wsb + 52 * MB); // s0 @0, s1 @4096, s2 @5120
  int* starts0 = starts;
  int* starts1 = starts + 4096;
  int* starts2 = starts + 5120;

  wtrans_all_k<<<7168, 256, 0, stream>>>(mlp_w1, mlp_w2, ca_w, w1t, w2t, cat);
  scan_all_k<<<dim3(4, 3), 1024, 0, stream>>>(b0, b1, b2, starts);

  // ---- levels: fused pool+LN, then MLP (mirror written by gemm2)
  auto mlp = [&](float* X, u16* mir, int Ntok, int lvl) {
    gemm_k<<<dim3(16, Ntok / 64), 256, 0, stream>>>(
        lnbuf, 512, w1t + (size_t)lvl * 524288, 512, 512,
        mlp_b1 + lvl * 1024, nullptr, hbuf, 1024, 1 | 8);
    gemm_k<<<dim3(8, Ntok / 64), 256, 0, stream>>>(
        hbuf, 1024, w2t + (size_t)lvl * 524288, 1024, 1024,
        mlp_b2 + lvl * 512, X, mir, 512, 2 | 4 | 8);
  };
  pool_ln_k<<<dim3(256, 4), 256, 0, stream>>>(h_bytes, starts0, out0,
      mlp_ln_g, mlp_ln_b, lnbuf, 8192, 1024);
  mlp(out0, m0b, 4096, 0);
  pool_ln_k<<<dim3(64, 4), 256, 0, stream>>>(out0, starts1, out1,
      mlp_ln_g + 512, mlp_ln_b + 512, lnbuf, 1024, 256);
  mlp(out1, m1b, 1024, 1);
  pool_ln_k<<<dim3(16, 4), 256, 0, stream>>>(out1, starts2, out2,
      mlp_ln_g + 1024, mlp_ln_b + 1024, lnbuf, 256, 64);
  mlp(out2, m2b, 256, 2);

  // ---- cross-level refinement
  auto cross = [&](int i, float* F, u16* mf, float* Cc, u16* mc, int nf, int nc) {
    u16* cw = cat + (size_t)i * 8 * 262144;
    const float* bb = ca_b + (size_t)i * 8 * 512;
    const float* lg = ca_ln_g + (size_t)i * 2 * 512;
    const float* lb = ca_ln_b + (size_t)i * 2 * 512;
    int Nf = 4 * nf, Nc = 4 * nc;
    // bottom-up: q = ln(F), kv from coarse mirror
    ln_kernel<<<Nf / 4, 256, 0, stream>>>(F, lg, lb, lnbuf, Nf);
    gemm_k<<<dim3(8, Nf / 64), 256, 0, stream>>>(lnbuf, 512, cw, 512, 512,
        bb, nullptr, qb, 512, 8);
    gemm_k<<<dim3(16, Nc / 64), 256, 0, stream>>>(mc, 512, cw + 262144, 512, 512,
        bb + 512, nullptr, kvbuf, 1024, 8);
    vtrans_kernel<<<dim3(nc / 32, 4, 16), 256, 0, stream>>>(kvbuf + 512, 1024, vT, nc);
    fattn_k<<<dim3(nf / 16, 16), 256, 0, stream>>>(qb, 512, kvbuf, 1024, vT,
        abuf, 512, nf, nc);
    gemm_k<<<dim3(8, Nf / 64), 256, 0, stream>>>(abuf, 512, cw + 3 * 262144, 512, 512,
        bb + 3 * 512, F, mf, 512, 2 | 4 | 8);
    // top-down: q = ln(Cc), kv from updated fine mirror
    ln_kernel<<<Nc / 4, 256, 0, stream>>>(Cc, lg + 512, lb + 512, lnbuf, Nc);
    gemm_k<<<dim3(8, Nc / 64), 256, 0, stream>>>(lnbuf, 512, cw + 4 * 262144, 512, 512,
        bb + 4 * 512, nullptr, qb, 512, 8);
    gemm_k<<<dim3(16, Nf / 64), 256, 0, stream>>>(mf, 512, cw + 5 * 262144, 512, 512,
        bb + 5 * 512, nullptr, kvbuf, 1024, 8);
    vtrans_kernel<<<dim3(nf / 32, 4, 16), 256, 0, stream>>>(kvbuf + 512, 1024, vT, nf);
    fattn_k<<<dim3(nc / 16, 16), 256, 0, stream>>>(qb, 512, kvbuf, 1024, vT,
        abuf, 512, nc, nf);
    gemm_k<<<dim3(8, Nc / 64), 256, 0, stream>>>(abuf, 512, cw + 7 * 262144, 512, 512,
        bb + 7 * 512, Cc, mc, 512, 2 | 4 | 8);
  };
  cross(1, out1, m1b, out2, m2b, 256, 64);
  cross(0, out0, m0b, out1, m1b, 1024, 256);
}

// Round 6
// 417.548 us; speedup vs baseline: 1.2506x; 1.0609x over previous
//
#include <hip/hip_runtime.h>
#include <hip/hip_bf16.h>
#include <math.h>

typedef __attribute__((ext_vector_type(8))) short bf16x8;
typedef __attribute__((ext_vector_type(4))) float f32x4;
typedef unsigned short u16;

__device__ __forceinline__ u16 f2b(float f) {
  unsigned u = __float_as_uint(f);
  u = u + 0x7fffu + ((u >> 16) & 1u);   // round-to-nearest-even
  return (u16)(u >> 16);
}
__device__ __forceinline__ float gelu_exact(float x) {
  return 0.5f * x * (1.0f + erff(x * 0.70710678118654752f));
}

struct GemmJob {
  const u16* A; const u16* Wt; const float* bias;
  float* Cf; u16* Cb; u16* vT;
  int lda, ldw, K, ldc, flags, bx, nblk, Skv;
};
struct LnJob { const float* x; const float* g; const float* b; u16* y; int ntok, nblk; };

// ---------------------------------------------------------------------------
// weight transposes (fp32 [K,M] -> bf16 [M,K]) + 3 boundary scans, one kernel.
// blocks 0..7167 transpose; 7168..7179 scan (lvl = j>>2, row = j&3).
__global__ __launch_bounds__(256) void wtrans_scan_k(
    const float* __restrict__ w1, const float* __restrict__ w2,
    const float* __restrict__ ca, u16* __restrict__ w1t,
    u16* __restrict__ w2t, u16* __restrict__ cat,
    const int* __restrict__ b0, const int* __restrict__ b1,
    const int* __restrict__ b2, int* __restrict__ starts) {
  __shared__ char smbuf[32 * 33 * 4];
  int z = blockIdx.x;
  if (z >= 7168) {
    int* sums = (int*)smbuf;
    int j = z - 7168, lvl = j >> 2, row = j & 3;
    const int* bp = (lvl == 0) ? b0 : (lvl == 1) ? b1 : b2;
    int n = (lvl == 0) ? 8192 : (lvl == 1) ? 1024 : 256;
    int nseg = (lvl == 0) ? 1024 : (lvl == 1) ? 256 : 64;
    int* sp = starts + ((lvl == 0) ? 0 : (lvl == 1) ? 4096 : 5120);
    const int* br = bp + (size_t)row * n;
    int chunk = n >> 8;                 // 32 / 4 / 1
    int t0 = threadIdx.x * chunk, t1 = t0 + chunk;
    int s = 0;
    for (int t = t0; t < t1; ++t) s += br[t];
    sums[threadIdx.x] = s;
    __syncthreads();
    for (int off = 1; off < 256; off <<= 1) {
      int v = (threadIdx.x >= off) ? sums[threadIdx.x - off] : 0;
      __syncthreads();
      sums[threadIdx.x] += v;
      __syncthreads();
    }
    int run = sums[threadIdx.x] - s;
    for (int t = t0; t < t1; ++t)
      if (br[t]) { sp[(size_t)row * nseg + run] = t; ++run; }
    return;
  }
  float (*tile)[33] = (float(*)[33])smbuf;
  const float* W; u16* Wt; int K, M, m0, k0;
  if (z < 1536) {
    int mat = z >> 9, tl = z & 511;
    W = w1 + (size_t)mat * 524288; Wt = w1t + (size_t)mat * 524288;
    K = 512; M = 1024; m0 = (tl & 31) * 32; k0 = (tl >> 5) * 32;
  } else if (z < 3072) {
    z -= 1536; int mat = z >> 9, tl = z & 511;
    W = w2 + (size_t)mat * 524288; Wt = w2t + (size_t)mat * 524288;
    K = 1024; M = 512; m0 = (tl & 15) * 32; k0 = (tl >> 4) * 32;
  } else {
    z -= 3072; int mat = z >> 8, tl = z & 255;
    W = ca + (size_t)mat * 262144; Wt = cat + (size_t)mat * 262144;
    K = 512; M = 512; m0 = (tl & 15) * 32; k0 = (tl >> 4) * 32;
  }
  int x = threadIdx.x & 31, y = threadIdx.x >> 5;
  #pragma unroll
  for (int i = 0; i < 32; i += 8)
    tile[y + i][x] = W[(size_t)(k0 + y + i) * M + m0 + x];
  __syncthreads();
  #pragma unroll
  for (int i = 0; i < 32; i += 8)
    Wt[(size_t)(m0 + y + i) * K + k0 + x] = f2b(tile[x][y + i]);
}

// ---------------------------------------------------------------------------
// fused segment-mean-pool + LayerNorm. one wave per segment.
__global__ __launch_bounds__(256) void pool_ln_k(
    const float* __restrict__ x, const int* __restrict__ starts,
    float* __restrict__ pooled, const float* __restrict__ g,
    const float* __restrict__ bt, u16* __restrict__ lnout,
    int Tin, int nseg) {
  int wv = threadIdx.x >> 6, lane = threadIdx.x & 63;
  int s = blockIdx.x * 4 + wv, b = blockIdx.y;
  int st = starts[(size_t)b * nseg + s];
  int en = (s + 1 < nseg) ? starts[(size_t)b * nseg + s + 1] : Tin;
  const float* xb = x + ((size_t)b * Tin) * 512;
  int d = lane * 8;
  float a[8] = {0.f,0.f,0.f,0.f,0.f,0.f,0.f,0.f};
  for (int t = st; t < en; ++t) {
    const float* row = xb + (size_t)t * 512 + d;
    float4 v0 = *(const float4*)row;
    float4 v1 = *(const float4*)(row + 4);
    a[0]+=v0.x; a[1]+=v0.y; a[2]+=v0.z; a[3]+=v0.w;
    a[4]+=v1.x; a[5]+=v1.y; a[6]+=v1.z; a[7]+=v1.w;
  }
  int cnt = en - st; if (cnt < 1) cnt = 1;
  float ic = 1.0f / (float)cnt;
  #pragma unroll
  for (int i = 0; i < 8; ++i) a[i] *= ic;
  int tok = b * nseg + s;
  float* pr = pooled + (size_t)tok * 512 + d;
  *(float4*)pr = make_float4(a[0], a[1], a[2], a[3]);
  *(float4*)(pr + 4) = make_float4(a[4], a[5], a[6], a[7]);
  float sm = a[0]+a[1]+a[2]+a[3]+a[4]+a[5]+a[6]+a[7];
  #pragma unroll
  for (int off = 32; off; off >>= 1) sm += __shfl_xor(sm, off, 64);
  float mean = sm * (1.0f / 512.0f);
  float ss = 0.f;
  #pragma unroll
  for (int i = 0; i < 8; ++i) { a[i] -= mean; ss += a[i]*a[i]; }
  #pragma unroll
  for (int off = 32; off; off >>= 1) ss += __shfl_xor(ss, off, 64);
  float inv = rsqrtf(ss * (1.0f / 512.0f) + 1e-5f);
  float4 g0 = *(const float4*)(g + d), g1 = *(const float4*)(g + d + 4);
  float4 b0 = *(const float4*)(bt + d), b1 = *(const float4*)(bt + d + 4);
  float gg[8] = {g0.x,g0.y,g0.z,g0.w,g1.x,g1.y,g1.z,g1.w};
  float bb[8] = {b0.x,b0.y,b0.z,b0.w,b1.x,b1.y,b1.z,b1.w};
  union { u16 u[8]; uint4 v; } pk;
  #pragma unroll
  for (int i = 0; i < 8; ++i) pk.u[i] = f2b(a[i] * inv * gg[i] + bb[i]);
  *(uint4*)(lnout + (size_t)tok * 512 + d) = pk.v;
}

// ---------------------------------------------------------------------------
// MFMA 64x64 tile core with next-tile prefetch. block=256, BK=64, 16x16x32.
__device__ __forceinline__ void mfma_core(
    const u16* __restrict__ A, int lda, const u16* __restrict__ Wt, int ldw,
    int K, u16* AsB, u16* WsB, f32x4 acc[2][2]) {
  int t = threadIdx.x;
  int lane = t & 63, wave = t >> 6;
  int wr = (wave >> 1) * 32, wc = (wave & 1) * 32;
  int lrow = t >> 3;
  int lseg = t & 7;
  int swz = (lseg * 16) ^ ((lrow & 7) << 4);
  const u16* Ap0 = A + (size_t)lrow * lda + lseg * 8;
  const u16* Ap1 = Ap0 + (size_t)32 * lda;
  const u16* Wp0 = Wt + (size_t)lrow * ldw + lseg * 8;
  const u16* Wp1 = Wp0 + (size_t)32 * ldw;
  uint4 a0 = *(const uint4*)(Ap0);
  uint4 a1 = *(const uint4*)(Ap1);
  uint4 w0 = *(const uint4*)(Wp0);
  uint4 w1 = *(const uint4*)(Wp1);
  for (int k0 = 0; k0 < K; k0 += 64) {
    __syncthreads();
    *(uint4*)((char*)AsB + lrow * 128 + swz) = a0;
    *(uint4*)((char*)AsB + (lrow + 32) * 128 + swz) = a1;
    *(uint4*)((char*)WsB + lrow * 128 + swz) = w0;
    *(uint4*)((char*)WsB + (lrow + 32) * 128 + swz) = w1;
    __syncthreads();
    if (k0 + 64 < K) {
      a0 = *(const uint4*)(Ap0 + k0 + 64);
      a1 = *(const uint4*)(Ap1 + k0 + 64);
      w0 = *(const uint4*)(Wp0 + k0 + 64);
      w1 = *(const uint4*)(Wp1 + k0 + 64);
    }
    #pragma unroll
    for (int ks = 0; ks < 2; ++ks) {
      bf16x8 af[2], bfr[2];
      #pragma unroll
      for (int mi = 0; mi < 2; ++mi) {
        int row = wr + mi * 16 + (lane & 15);
        int cb = (ks * 64 + ((lane >> 4) << 4)) ^ ((row & 7) << 4);
        af[mi] = *(const bf16x8*)((const char*)AsB + row * 128 + cb);
      }
      #pragma unroll
      for (int ni = 0; ni < 2; ++ni) {
        int row = wc + ni * 16 + (lane & 15);
        int cb = (ks * 64 + ((lane >> 4) << 4)) ^ ((row & 7) << 4);
        bfr[ni] = *(const bf16x8*)((const char*)WsB + row * 128 + cb);
      }
      #pragma unroll
      for (int mi = 0; mi < 2; ++mi)
        #pragma unroll
        for (int ni = 0; ni < 2; ++ni)
          acc[mi][ni] = __builtin_amdgcn_mfma_f32_16x16x32_bf16(
              af[mi], bfr[ni], acc[mi][ni], 0, 0, 0);
    }
  }
}

// ---------------------------------------------------------------------------
// GEMM body: C = act(A @ Wt^T + bias). flags: 1=GELU 2=RES 4=outF 8=outB
// 16=V-transpose epilogue for m0>=512 (writes vT[bh][d][kv] directly).
__device__ __forceinline__ void gemm_body(const GemmJob& J, int mx, int my,
                                          char* smem) {
  u16* As = (u16*)smem;
  u16* Ws = As + 4096;
  int n0 = my * 64, m0 = mx * 64;
  f32x4 acc[2][2];
  #pragma unroll
  for (int i = 0; i < 2; ++i)
    #pragma unroll
    for (int j = 0; j < 2; ++j) acc[i][j] = (f32x4){0.f, 0.f, 0.f, 0.f};
  mfma_core(J.A + (size_t)n0 * J.lda, J.lda, J.Wt + (size_t)m0 * J.ldw, J.ldw,
            J.K, As, Ws, acc);
  int lane = threadIdx.x & 63, wave = threadIdx.x >> 6;
  int wr = (wave >> 1) * 32, wc = (wave & 1) * 32;
  if ((J.flags & 16) && m0 >= 512) {
    // stage bf16 C tile to LDS [token][d] (stride 72), then write transposed
    __syncthreads();
    u16* tile = (u16*)smem;
    #pragma unroll
    for (int mi = 0; mi < 2; ++mi)
      #pragma unroll
      for (int ni = 0; ni < 2; ++ni) {
        int tc = wc + ni * 16 + (lane & 15);
        float bv = J.bias[m0 + tc];
        #pragma unroll
        for (int j = 0; j < 4; ++j) {
          int tr = wr + mi * 16 + ((lane >> 4) << 2) + j;
          tile[tr * 72 + tc] = f2b(acc[mi][ni][j] + bv);
        }
      }
    __syncthreads();
    int h = (m0 - 512) >> 7, d0i = (m0 - 512) & 127;
    int b = n0 / J.Skv, tok0 = n0 % J.Skv;
    int z = b * 4 + h;
    int d = threadIdx.x >> 2, tkb = (threadIdx.x & 3) * 16;
    u16* dst = J.vT + ((size_t)z * 128 + d0i + d) * J.Skv + tok0 + tkb;
    union { u16 u[16]; uint4 v[2]; } pk;
    #pragma unroll
    for (int t2 = 0; t2 < 16; ++t2) pk.u[t2] = tile[(tkb + t2) * 72 + d];
    *(uint4*)dst = pk.v[0];
    *(uint4*)(dst + 8) = pk.v[1];
    return;
  }
  #pragma unroll
  for (int mi = 0; mi < 2; ++mi) {
    #pragma unroll
    for (int ni = 0; ni < 2; ++ni) {
      int col = m0 + wc + ni * 16 + (lane & 15);
      float bv = J.bias[col];
      #pragma unroll
      for (int j = 0; j < 4; ++j) {
        int row = n0 + wr + mi * 16 + ((lane >> 4) << 2) + j;
        float v = acc[mi][ni][j] + bv;
        if (J.flags & 1) v = gelu_exact(v);
        size_t idx = (size_t)row * J.ldc + col;
        if (J.flags & 2) v += J.Cf[idx];
        if (J.flags & 4) J.Cf[idx] = v;
        if (J.flags & 8) J.Cb[idx] = f2b(v);
      }
    }
  }
}

// ---------------------------------------------------------------------------
// LayerNorm body: fp32 in -> bf16 out. one wave per token, 4 tokens/block.
__device__ __forceinline__ void ln_body(const LnJob& L, int bid) {
  int wave = threadIdx.x >> 6, lane = threadIdx.x & 63;
  int tok = bid * 4 + wave;
  if (tok >= L.ntok) return;
  const float* xr = L.x + (size_t)tok * 512;
  int d = lane * 8;
  float4 v0 = *(const float4*)(xr + d);
  float4 v1 = *(const float4*)(xr + d + 4);
  float s = v0.x + v0.y + v0.z + v0.w + v1.x + v1.y + v1.z + v1.w;
  #pragma unroll
  for (int off = 32; off; off >>= 1) s += __shfl_xor(s, off, 64);
  float mean = s * (1.0f / 512.0f);
  float a[8] = {v0.x-mean, v0.y-mean, v0.z-mean, v0.w-mean,
                v1.x-mean, v1.y-mean, v1.z-mean, v1.w-mean};
  float ss = 0.f;
  #pragma unroll
  for (int i = 0; i < 8; ++i) ss += a[i]*a[i];
  #pragma unroll
  for (int off = 32; off; off >>= 1) ss += __shfl_xor(ss, off, 64);
  float inv = rsqrtf(ss * (1.0f / 512.0f) + 1e-5f);
  float4 g0 = *(const float4*)(L.g + d), g1 = *(const float4*)(L.g + d + 4);
  float4 b0 = *(const float4*)(L.b + d), b1 = *(const float4*)(L.b + d + 4);
  float gg[8] = {g0.x,g0.y,g0.z,g0.w,g1.x,g1.y,g1.z,g1.w};
  float bb[8] = {b0.x,b0.y,b0.z,b0.w,b1.x,b1.y,b1.z,b1.w};
  union { u16 u[8]; uint4 v; } pk;
  #pragma unroll
  for (int i = 0; i < 8; ++i) pk.u[i] = f2b(a[i] * inv * gg[i] + bb[i]);
  *(uint4*)(L.y + (size_t)tok * 512 + d) = pk.v;
}

// ---------------------------------------------------------------------------
// job-batched kernel: [0,L.nblk) = LN, [L.nblk,+A.nblk) = gemm A, rest = B.
__global__ __launch_bounds__(256) void fused_k(LnJob L, GemmJob A, GemmJob B) {
  __shared__ char smem[16384];
  int bid = blockIdx.x;
  if (bid < L.nblk) { ln_body(L, bid); return; }
  bid -= L.nblk;
  if (bid < A.nblk) {
    gemm_body(A, bid % A.bx, bid / A.bx, smem);
  } else {
    bid -= A.nblk;
    gemm_body(B, bid % B.bx, bid / B.bx, smem);
  }
}

// ---------------------------------------------------------------------------
// fused attention, split-KV, barrier-free main loop (see r5 notes).
__global__ __launch_bounds__(256) void fattn_k(
    const u16* __restrict__ Q, int ldq, const u16* __restrict__ KV, int ldkv,
    const u16* __restrict__ vT, u16* __restrict__ O, int ldo,
    int Sq, int Skv) {
  __shared__ u16 Ps[4][16 * 64];
  __shared__ float Ob[3][8][16][16];
  __shared__ float Ls[3][16];
  int z = blockIdx.y, b = z >> 2, h = z & 3;
  int t = threadIdx.x, lane = t & 63, w = t >> 6;
  int g = lane >> 4, ql = lane & 15;
  int q0 = blockIdx.x * 16;
  const float scale = 0.08838834764831845f;
  bf16x8 qf[4];
  {
    const u16* qp = Q + ((size_t)(b * Sq + q0 + ql)) * ldq + h * 128 + g * 8;
    #pragma unroll
    for (int ks = 0; ks < 4; ++ks) qf[ks] = *(const bf16x8*)(qp + 32 * ks);
  }
  f32x4 o[8];
  #pragma unroll
  for (int i = 0; i < 8; ++i) o[i] = (f32x4){0.f, 0.f, 0.f, 0.f};
  float lsum = 0.f;
  int ntiles = Skv >> 6;
  const u16* kbaseA = KV + ((size_t)b * Skv + ql) * ldkv + h * 128 + g * 8;
  const u16* vbase = vT + (size_t)z * 128 * Skv;
  for (int tt = w; tt < ntiles; tt += 4) {
    int kv0 = tt * 64;
    float rs = 0.f;
    #pragma unroll
    for (int kvt = 0; kvt < 4; ++kvt) {
      const u16* kp = kbaseA + (size_t)(kv0 + kvt * 16) * ldkv;
      f32x4 acc = (f32x4){0.f, 0.f, 0.f, 0.f};
      #pragma unroll
      for (int ks = 0; ks < 4; ++ks) {
        bf16x8 kf = *(const bf16x8*)(kp + 32 * ks);
        acc = __builtin_amdgcn_mfma_f32_16x16x32_bf16(kf, qf[ks], acc, 0, 0, 0);
      }
      float e0 = __expf(acc[0] * scale), e1 = __expf(acc[1] * scale);
      float e2 = __expf(acc[2] * scale), e3 = __expf(acc[3] * scale);
      rs += e0 + e1 + e2 + e3;
      unsigned lo = (unsigned)f2b(e0) | ((unsigned)f2b(e1) << 16);
      unsigned hi = (unsigned)f2b(e2) | ((unsigned)f2b(e3) << 16);
      int slot = (2 * kvt + (g >> 1)) ^ (ql & 7);
      *(uint2*)((char*)Ps[w] + ql * 128 + slot * 16 + 8 * (g & 1)) =
          make_uint2(lo, hi);
    }
    rs += __shfl_xor(rs, 16, 64);
    rs += __shfl_xor(rs, 32, 64);
    lsum += rs;
    #pragma unroll
    for (int kh = 0; kh < 2; ++kh) {
      int slot = (4 * kh + g) ^ (ql & 7);
      bf16x8 pa = *(const bf16x8*)((const char*)Ps[w] + ql * 128 + slot * 16);
      #pragma unroll
      for (int dt = 0; dt < 8; ++dt) {
        bf16x8 vf = *(const bf16x8*)(vbase + (size_t)(dt * 16 + ql) * Skv +
                                     kv0 + kh * 32 + g * 8);
        o[dt] = __builtin_amdgcn_mfma_f32_16x16x32_bf16(pa, vf, o[dt], 0, 0, 0);
      }
    }
  }
  if (w) {
    #pragma unroll
    for (int dt = 0; dt < 8; ++dt)
      #pragma unroll
      for (int j = 0; j < 4; ++j)
        Ob[w - 1][dt][4 * g + j][ql] = o[dt][j];
    if (g == 0) Ls[w - 1][ql] = lsum;
  }
  __syncthreads();
  if (w == 0) {
    float lt = lsum + Ls[0][ql] + Ls[1][ql] + Ls[2][ql];
    float linv[4];
    #pragma unroll
    for (int r = 0; r < 4; ++r) linv[r] = 1.0f / __shfl(lt, 4 * g + r, 64);
    u16* ob = O + ((size_t)(b * Sq + q0)) * ldo + h * 128;
    #pragma unroll
    for (int dt = 0; dt < 8; ++dt)
      #pragma unroll
      for (int r = 0; r < 4; ++r) {
        float v = o[dt][r] + Ob[0][dt][4 * g + r][ql] +
                  Ob[1][dt][4 * g + r][ql] + Ob[2][dt][4 * g + r][ql];
        ob[(size_t)(4 * g + r) * ldo + dt * 16 + ql] = f2b(v * linv[r]);
      }
  }
}

// ---------------------------------------------------------------------------
extern "C" void kernel_launch(void* const* d_in, const int* in_sizes, int n_in,
                              void* d_out, int out_size, void* d_ws, size_t ws_size,
                              hipStream_t stream) {
  (void)in_sizes; (void)n_in; (void)out_size; (void)ws_size;
  const float* h_bytes  = (const float*)d_in[0];
  const int*   b0       = (const int*)d_in[1];
  const int*   b1       = (const int*)d_in[2];
  const int*   b2       = (const int*)d_in[3];
  const float* mlp_ln_g = (const float*)d_in[4];
  const float* mlp_ln_b = (const float*)d_in[5];
  const float* mlp_w1   = (const float*)d_in[6];
  const float* mlp_b1   = (const float*)d_in[7];
  const float* mlp_w2   = (const float*)d_in[8];
  const float* mlp_b2   = (const float*)d_in[9];
  const float* ca_w     = (const float*)d_in[10];
  const float* ca_b     = (const float*)d_in[11];
  const float* ca_ln_g  = (const float*)d_in[12];
  const float* ca_ln_b  = (const float*)d_in[13];

  float* out0 = (float*)d_out;
  float* out1 = out0 + 4 * 1024 * 512;
  float* out2 = out1 + 4 * 256 * 512;

  char* wsb = (char*)d_ws;
  const size_t MB = 1048576;
  u16* w1t   = (u16*)(wsb + 0 * MB);    // [3][1024][512]
  u16* w2t   = (u16*)(wsb + 3 * MB);    // [3][512][1024]
  u16* cat   = (u16*)(wsb + 6 * MB);    // [16][512][512]
  u16* m0b   = (u16*)(wsb + 14 * MB);   // bf16 mirror of out0
  u16* m1b   = (u16*)(wsb + 18 * MB);   // mirror of out1
  u16* m2b   = (u16*)(wsb + 19 * MB);   // mirror of out2
  u16* lnbuf = (u16*)(wsb + 20 * MB);
  u16* hbuf  = (u16*)(wsb + 24 * MB);
  u16* qb    = (u16*)(wsb + 32 * MB);
  u16* kbuf  = (u16*)(wsb + 36 * MB);   // [N][512] K-proj
  u16* vT    = (u16*)(wsb + 44 * MB);   // [16][128][Skv]
  u16* abuf  = (u16*)(wsb + 48 * MB);
  int* starts  = (int*)(wsb + 52 * MB);
  int* starts0 = starts;
  int* starts1 = starts + 4096;
  int* starts2 = starts + 5120;

  auto mkgemm = [](const u16* A, int lda, const u16* Wt, int ldw, int K,
                   const float* bias, float* Cf, u16* Cb, int ldc, int flags,
                   int rows, int M, u16* vTp = nullptr, int Skv = 0) {
    GemmJob j; j.A = A; j.lda = lda; j.Wt = Wt; j.ldw = ldw; j.K = K;
    j.bias = bias; j.Cf = Cf; j.Cb = Cb; j.ldc = ldc; j.flags = flags;
    j.bx = M / 64; j.nblk = (M / 64) * (rows / 64); j.vT = vTp; j.Skv = Skv;
    return j;
  };
  auto mkln = [](const float* x, const float* g, const float* b, u16* y,
                 int ntok) {
    LnJob l; l.x = x; l.g = g; l.b = b; l.y = y; l.ntok = ntok;
    l.nblk = ntok / 4; return l;
  };
  GemmJob gz = {}; gz.nblk = 0; gz.bx = 1;
  LnJob lz = {}; lz.nblk = 0;
  auto launch = [&](LnJob L, GemmJob A, GemmJob B) {
    fused_k<<<L.nblk + A.nblk + B.nblk, 256, 0, stream>>>(L, A, B);
  };

  // L1: weights + scans
  wtrans_scan_k<<<7180, 256, 0, stream>>>(mlp_w1, mlp_w2, ca_w, w1t, w2t, cat,
                                          b0, b1, b2, starts);

  // ---- levels (serial): pool+LN, MLP gemm1 (GELU), gemm2 (res)
  pool_ln_k<<<dim3(256, 4), 256, 0, stream>>>(h_bytes, starts0, out0,
      mlp_ln_g, mlp_ln_b, lnbuf, 8192, 1024);
  launch(lz, mkgemm(lnbuf, 512, w1t, 512, 512, mlp_b1, nullptr, hbuf, 1024,
                    1 | 8, 4096, 1024), gz);
  launch(lz, mkgemm(hbuf, 1024, w2t, 1024, 1024, mlp_b2, out0, nullptr, 512,
                    2 | 4, 4096, 512), gz);
  pool_ln_k<<<dim3(64, 4), 256, 0, stream>>>(out0, starts1, out1,
      mlp_ln_g + 512, mlp_ln_b + 512, lnbuf, 1024, 256);
  launch(lz, mkgemm(lnbuf, 512, w1t + 524288, 512, 512, mlp_b1 + 1024,
                    nullptr, hbuf, 1024, 1 | 8, 1024, 1024), gz);
  launch(lz, mkgemm(hbuf, 1024, w2t + 524288, 1024, 1024, mlp_b2 + 512, out1,
                    nullptr, 512, 2 | 4, 1024, 512), gz);
  pool_ln_k<<<dim3(16, 4), 256, 0, stream>>>(out1, starts2, out2,
      mlp_ln_g + 1024, mlp_ln_b + 1024, lnbuf, 256, 64);
  launch(lz, mkgemm(lnbuf, 512, w1t + 2 * 524288, 512, 512, mlp_b1 + 2048,
                    nullptr, hbuf, 1024, 1 | 8, 256, 1024), gz);
  launch(lz, mkgemm(hbuf, 1024, w2t + 2 * 524288, 1024, 1024, mlp_b2 + 1024,
                    out2, m2b, 512, 2 | 4 | 8, 256, 512), gz);

  // ---- cross-level refinement (i=1 then i=0); per direction:
  //   [ln + KVproj(K->kbuf, V->vT)] ; [Qproj] ; fattn ; [outproj + next-ln]
  const size_t WS = 262144;
  // cross1 (nf=256, nc=64) bottom-up
  {
    u16* cw = cat + 8 * WS;
    const float* bb = ca_b + 8 * 512;
    launch(mkln(out1, ca_ln_g + 1024, ca_ln_b + 1024, lnbuf, 1024),
           mkgemm(m2b, 512, cw + WS, 512, 512, bb + 512, nullptr, kbuf, 512,
                  8 | 16, 256, 1024, vT, 64), gz);
    launch(lz, mkgemm(lnbuf, 512, cw, 512, 512, bb, nullptr, qb, 512, 8,
                      1024, 512), gz);
    fattn_k<<<dim3(16, 16), 256, 0, stream>>>(qb, 512, kbuf, 512, vT, abuf,
                                              512, 256, 64);
    // bu outproj -> out1 + m1b ; batched with td ln(out2)
    launch(mkln(out2, ca_ln_g + 1536, ca_ln_b + 1536, lnbuf, 256),
           mkgemm(abuf, 512, cw + 3 * WS, 512, 512, bb + 3 * 512, out1, m1b,
                  512, 2 | 4 | 8, 1024, 512), gz);
    // td: Qproj(lnbuf rows 256) + KVproj(m1b rows 1024 -> kbuf,vT Skv=256)
    launch(lz, mkgemm(lnbuf, 512, cw + 4 * WS, 512, 512, bb + 4 * 512,
                      nullptr, qb, 512, 8, 256, 512),
           mkgemm(m1b, 512, cw + 5 * WS, 512, 512, bb + 5 * 512, nullptr,
                  kbuf, 512, 8 | 16, 1024, 1024, vT, 256));
    fattn_k<<<dim3(4, 16), 256, 0, stream>>>(qb, 512, kbuf, 512, vT, abuf,
                                             512, 64, 256);
    // td outproj -> out2 (final) ; batched with cross0 bu ln(out0)
    launch(mkln(out0, ca_ln_g, ca_ln_b, lnbuf, 4096),
           mkgemm(abuf, 512, cw + 7 * WS, 512, 512, bb + 7 * 512, out2,
                  nullptr, 512, 2 | 4, 256, 512), gz);
  }
  // cross0 (nf=1024, nc=256)
  {
    u16* cw = cat;
    const float* bb = ca_b;
    // bu: Qproj(lnbuf rows 4096) + KVproj(m1b rows 1024 -> kbuf,vT Skv=256)
    launch(lz, mkgemm(lnbuf, 512, cw, 512, 512, bb, nullptr, qb, 512, 8,
                      4096, 512),
           mkgemm(m1b, 512, cw + WS, 512, 512, bb + 512, nullptr, kbuf, 512,
                  8 | 16, 1024, 1024, vT, 256));
    fattn_k<<<dim3(64, 16), 256, 0, stream>>>(qb, 512, kbuf, 512, vT, abuf,
                                              512, 1024, 256);
    // bu outproj -> out0 (final) + m0b ; batched with td ln(out1)
    launch(mkln(out1, ca_ln_g + 512, ca_ln_b + 512, lnbuf, 1024),
           mkgemm(abuf, 512, cw + 3 * WS, 512, 512, bb + 3 * 512, out0, m0b,
                  512, 2 | 4 | 8, 4096, 512), gz);
    // td: Qproj(lnbuf rows 1024) + KVproj(m0b rows 4096 -> kbuf,vT Skv=1024)
    launch(lz, mkgemm(lnbuf, 512, cw + 4 * WS, 512, 512, bb + 4 * 512,
                      nullptr, qb, 512, 8, 1024, 512),
           mkgemm(m0b, 512, cw + 5 * WS, 512, 512, bb + 5 * 512, nullptr,
                  kbuf, 512, 8 | 16, 4096, 1024, vT, 1024));
    fattn_k<<<dim3(16, 16), 256, 0, stream>>>(qb, 512, kbuf, 512, vT, abuf,
                                              512, 256, 1024);
    // td outproj -> out1 (final)
    launch(lz, mkgemm(abuf, 512, cw + 7 * WS, 512, 512, bb + 7 * 512, out1,
                      nullptr, 512, 2 | 4, 1024, 512), gz);
  }
}